// Round 4
// baseline (362.114 us; speedup 1.0000x reference)
//
#include <hip/hip_runtime.h>
#include <hip/hip_bf16.h>
#include <stdint.h>

typedef __attribute__((ext_vector_type(8))) __bf16 bf16x8;
typedef __attribute__((ext_vector_type(4))) float f32x4;

#define KP 4160   // padded K: 4096 (quantized x) + 32 (lora T) + 32 (zero pad)

__device__ inline void async_copy16(const void* g, void* l) {
  __builtin_amdgcn_global_load_lds((const __attribute__((address_space(1))) void*)g,
                                   (__attribute__((address_space(3))) void*)l, 16, 0, 0);
}

// ---------------------------------------------------------------------------
// Kernel 1: SmoothQuant scale + NVFP4 fake-quant -> bf16 into A_big[:, 0:4096]
// One thread per 16-element block (exactly replicates reference fp32 math).
// Block b handles exactly row b; threads 0-31 additionally perform the LoRA
// partial-sum fixup for row b (T -> Ab[:,4096:4128], zeros -> 4128:4160),
// replacing the former lora_fix_kernel (same kc summation order -> identical
// bits).
// ---------------------------------------------------------------------------
__global__ __launch_bounds__(256) void quant_kernel(const float* __restrict__ x,
                                                    const float* __restrict__ ss,
                                                    const float* __restrict__ Tp,
                                                    __bf16* __restrict__ Ab) {
  int row = blockIdx.x;                 // 4096 blocks, one per row
  int tid = threadIdx.x;
  int col = tid << 4;
  const float4* xp = (const float4*)(x + ((size_t)row << 12) + col);
  const float4* sp = (const float4*)(ss + col);
  float xs[16];
#pragma unroll
  for (int i = 0; i < 4; i++) {
    float4 xv = xp[i]; float4 sv = sp[i];
    xs[4*i+0] = xv.x * sv.x; xs[4*i+1] = xv.y * sv.y;
    xs[4*i+2] = xv.z * sv.z; xs[4*i+3] = xv.w * sv.w;
  }
  float amax = 0.f;
#pragma unroll
  for (int i = 0; i < 16; i++) amax = fmaxf(amax, fabsf(xs[i]));
  amax = fmaxf(amax, 1e-12f);
  float scale = amax / 6.0f;                  // IEEE fp32 divide, same as np
  bf16x8 o0, o1;
#pragma unroll
  for (int i = 0; i < 16; i++) {
    float a  = fabsf(xs[i]);
    float xn = a / scale;                     // IEEE fp32 divide, same as np
    // literal argmin over the 8 levels, strict < keeps first on ties (np.argmin)
    float bestd = xn;                         // |xn - 0.0|
    float lvl   = 0.f;
    const float L[7] = {0.5f, 1.f, 1.5f, 2.f, 3.f, 4.f, 6.f};
#pragma unroll
    for (int j = 0; j < 7; j++) {
      float d = fabsf(xn - L[j]);
      if (d < bestd) { bestd = d; lvl = L[j]; }
    }
    float mag = lvl * scale;
    float q = (xs[i] > 0.f) ? mag : ((xs[i] < 0.f) ? -mag : 0.f);
    if (i < 8) o0[i] = (__bf16)q; else o1[i-8] = (__bf16)q;
  }
  __bf16* dst = Ab + (size_t)row * KP + col;
  *(bf16x8*)dst = o0;
  *(bf16x8*)(dst + 8) = o1;
  // fused lora_fix: sum the 8 K-chunk partials for this row (same order as
  // the old lora_fix_kernel -> bit-identical), write T + zero pad.
  if (tid < 32) {
    float s = 0.f;
#pragma unroll
    for (int kc = 0; kc < 8; kc++)
      s += Tp[((size_t)kc * 4096 + row) * 32 + tid];
    __bf16* td = Ab + (size_t)row * KP + 4096;
    td[tid]      = (__bf16)s;
    td[32 + tid] = (__bf16)0.f;
  }
}

// ---------------------------------------------------------------------------
// Kernel 2: w fp32 -> bf16 into B_big[:, 0:4096]; lora_b -> cols 4096:4128;
// zeros -> cols 4128:4160.  Runs AFTER quant (overwrites the aliased Tp).
// ---------------------------------------------------------------------------
__global__ __launch_bounds__(256) void wconv_kernel(const float* __restrict__ w,
                                                    const float* __restrict__ lb,
                                                    __bf16* __restrict__ Bb) {
  int id  = blockIdx.x * 256 + threadIdx.x;   // < 4096*520
  int row = id / 520;
  int g   = id - row * 520;
  bf16x8 v;
  if (g < 512) {
    const float4* wp = (const float4*)(w + ((size_t)row << 12) + (g << 3));
    float4 a = wp[0], b = wp[1];
    v[0]=(__bf16)a.x; v[1]=(__bf16)a.y; v[2]=(__bf16)a.z; v[3]=(__bf16)a.w;
    v[4]=(__bf16)b.x; v[5]=(__bf16)b.y; v[6]=(__bf16)b.z; v[7]=(__bf16)b.w;
  } else if (g < 516) {
    const float* p = lb + (size_t)row * 32 + ((g - 512) << 3);
#pragma unroll
    for (int j = 0; j < 8; j++) v[j] = (__bf16)p[j];
  } else {
#pragma unroll
    for (int j = 0; j < 8; j++) v[j] = (__bf16)0.f;
  }
  *(bf16x8*)(Bb + (size_t)row * KP + ((size_t)g << 3)) = v;
}

// ---------------------------------------------------------------------------
// Kernel 3: K-split LoRA partials.  grid (256 m-strips, 8 k-chunks), 4 waves.
// Each block: rows m0..m0+15, K window of 512 (128 per wave), MFMA 16x16x32,
// LDS-reduce 4 waves -> fp32 partial [16][32] -> Tp[kc][4096][32].
// Tp ALIASES the start of Bb (dead until wconv runs later) so total ws stays
// at the round-1-proven 136.3 MB.
// ---------------------------------------------------------------------------
__global__ __launch_bounds__(256) void lora_part_kernel(const float* __restrict__ x,
                                                        const float* __restrict__ ss,
                                                        const float* __restrict__ la,
                                                        float* __restrict__ Tp) {
  __shared__ float red[4][16][32];
  int tid  = threadIdx.x;
  int wave = tid >> 6, lane = tid & 63;
  int lrow = lane & 15, kg = lane >> 4;
  int m0 = blockIdx.x << 4;
  int kbase = (blockIdx.y << 9) + (wave << 7);
  f32x4 acc0 = {0.f,0.f,0.f,0.f}, acc1 = {0.f,0.f,0.f,0.f};
  const float* xrow = x + ((size_t)(m0 + lrow) << 12);
  const float* a0   = la + ((size_t)lrow << 12);
  const float* a1   = a0 + (16 << 12);
#pragma unroll
  for (int k0 = 0; k0 < 128; k0 += 32) {
    int kk = kbase + k0 + (kg << 3);
    float xv[8], sv[8], v0[8], v1[8];
    *(float4*)&xv[0] = *(const float4*)(xrow + kk);
    *(float4*)&xv[4] = *(const float4*)(xrow + kk + 4);
    *(float4*)&sv[0] = *(const float4*)(ss + kk);
    *(float4*)&sv[4] = *(const float4*)(ss + kk + 4);
    *(float4*)&v0[0] = *(const float4*)(a0 + kk);
    *(float4*)&v0[4] = *(const float4*)(a0 + kk + 4);
    *(float4*)&v1[0] = *(const float4*)(a1 + kk);
    *(float4*)&v1[4] = *(const float4*)(a1 + kk + 4);
    bf16x8 af, b0, b1;
#pragma unroll
    for (int j = 0; j < 8; j++) {
      af[j] = (__bf16)(xv[j] * sv[j]);
      b0[j] = (__bf16)v0[j];
      b1[j] = (__bf16)v1[j];
    }
    acc0 = __builtin_amdgcn_mfma_f32_16x16x32_bf16(af, b0, acc0, 0, 0, 0);
    acc1 = __builtin_amdgcn_mfma_f32_16x16x32_bf16(af, b1, acc1, 0, 0, 0);
  }
#pragma unroll
  for (int r = 0; r < 4; r++) {
    red[wave][kg*4 + r][lrow]      = acc0[r];   // verified layout (rounds 1-3)
    red[wave][kg*4 + r][16 + lrow] = acc1[r];
  }
  __syncthreads();
  for (int o = tid; o < 512; o += 256) {
    int rr = o >> 5, cc = o & 31;
    float s = red[0][rr][cc] + red[1][rr][cc] + red[2][rr][cc] + red[3][rr][cc];
    Tp[((size_t)blockIdx.y * 4096 + m0 + rr) * 32 + cc] = s;
  }
}

// ---------------------------------------------------------------------------
// Kernel 4: C[4096,4096] = A_big @ B_big^T + bias.  m97 structure (verified
// rounds 1-3: 0 LDS bank conflicts, ~173 us, MfmaUtil 35%).  NEW this round:
// grouped block swizzle (GROUP_M=8) — with round-robin block->XCD dispatch,
// each XCD keeps one A-tile L2-resident across a full bn sweep.
// ---------------------------------------------------------------------------
__global__ __launch_bounds__(256) void gemm_kernel(const __bf16* __restrict__ A,
                                                   const __bf16* __restrict__ B,
                                                   const float* __restrict__ bias,
                                                   float* __restrict__ C) {
  __shared__ __bf16 As[128 * 64];
  __shared__ __bf16 Bs[128 * 64];
  int tid  = threadIdx.x;
  int wave = tid >> 6, lane = tid & 63;
  // grouped swizzle: 1024 blocks = 4 groups x (8 bm x 32 bn)
  int g        = blockIdx.x;
  int group_id = g >> 8;                      // / (8*32)
  int lg       = g & 255;
  int bm = (group_id << 3) + (lg & 7);
  int bn = lg >> 3;
  size_t m0 = (size_t)bm << 7, n0 = (size_t)bn << 7;
  int wm = wave >> 1, wn = wave & 1;
  int lrow = lane & 15, kg = lane >> 4;
  int srow = lane >> 3;                       // row within 8-row staging chunk
  int sk   = ((lane & 7) ^ srow) << 3;        // swizzled k element offset
  f32x4 acc[4][4];
#pragma unroll
  for (int r = 0; r < 4; r++)
#pragma unroll
    for (int c = 0; c < 4; c++) acc[r][c] = (f32x4){0.f,0.f,0.f,0.f};

  for (int k = 0; k < KP; k += 64) {
#pragma unroll
    for (int i = 0; i < 4; i++) {
      int chunk = (wave << 2) + i;            // 16 chunks of 8 rows x 64 k
      int row   = (chunk << 3) + srow;
      async_copy16(A + (m0 + row) * (size_t)KP + k + sk, (void*)(As + chunk * 512));
      async_copy16(B + (n0 + row) * (size_t)KP + k + sk, (void*)(Bs + chunk * 512));
    }
    __syncthreads();
#pragma unroll
    for (int ks = 0; ks < 2; ks++) {
      bf16x8 af[4], bfr[4];
      int kx = ((ks << 6) + (kg << 4)) ^ ((lrow & 7) << 4);
#pragma unroll
      for (int r = 0; r < 4; r++) {
        int ml = (wm << 6) + (r << 4) + lrow;
        af[r]  = *(const bf16x8*)((const char*)As + ml * 128 + kx);
        int nl = (wn << 6) + (r << 4) + lrow;
        bfr[r] = *(const bf16x8*)((const char*)Bs + nl * 128 + kx);
      }
#pragma unroll
      for (int r = 0; r < 4; r++)
#pragma unroll
        for (int c = 0; c < 4; c++)
          acc[r][c] = __builtin_amdgcn_mfma_f32_16x16x32_bf16(af[r], bfr[c], acc[r][c], 0, 0, 0);
    }
    __syncthreads();
  }
  // epilogue: + bias, fp32 store. C frag layout: col=lane&15, row=kg*4+reg.
#pragma unroll
  for (int c = 0; c < 4; c++) {
    int col = (int)n0 + (wn << 6) + (c << 4) + lrow;
    float bv = bias[col];
#pragma unroll
    for (int r = 0; r < 4; r++) {
      size_t rowb = m0 + (wm << 6) + (r << 4) + (kg << 2);
#pragma unroll
      for (int q = 0; q < 4; q++)
        C[(rowb + q) * 4096 + col] = acc[r][c][q] + bv;
    }
  }
}

extern "C" void kernel_launch(void* const* d_in, const int* in_sizes, int n_in,
                              void* d_out, int out_size, void* d_ws, size_t ws_size,
                              hipStream_t stream) {
  const float* x    = (const float*)d_in[0];   // [2,2048,4096]
  const float* ss   = (const float*)d_in[1];   // [4096]
  const float* w    = (const float*)d_in[2];   // [4096,4096]
  const float* la   = (const float*)d_in[3];   // [32,4096]
  const float* lb   = (const float*)d_in[4];   // [4096,32]
  const float* bias = (const float*)d_in[5];   // [4096]
  float* out = (float*)d_out;                  // [2,2048,4096] fp32

  __bf16* Ab = (__bf16*)d_ws;                  // [4096, 4160] bf16  (34.1 MB)
  __bf16* Bb = Ab + (size_t)4096 * KP;         // [4096, 4160] bf16  (34.1 MB)
  // Tp ALIASES the first 4 MB of Bb — dead until wconv runs (after quant's
  // fused fixup).  Total ws usage = 136,314,880 B (proven to fit in round 1).
  float* Tp = (float*)Bb;                      // [8][4096][32] fp32 (4 MB)

  lora_part_kernel<<<dim3(256, 8), 256, 0, stream>>>(x, ss, la, Tp);
  quant_kernel<<<4096, 256, 0, stream>>>(x, ss, Tp, Ab);   // + fused lora_fix
  wconv_kernel<<<8320, 256, 0, stream>>>(w, lb, Bb);       // overwrites Tp
  gemm_kernel<<<1024, 256, 0, stream>>>(Ab, Bb, bias, out);
}

// Round 5
// 354.179 us; speedup vs baseline: 1.0224x; 1.0224x over previous
//
#include <hip/hip_runtime.h>
#include <hip/hip_bf16.h>
#include <stdint.h>

typedef __attribute__((ext_vector_type(8))) __bf16 bf16x8;
typedef __attribute__((ext_vector_type(4))) float f32x4;

#define KP 4160   // padded K: 4096 (quantized x) + 32 (lora T) + 32 (zero pad)

__device__ inline void async_copy16(const void* g, void* l) {
  __builtin_amdgcn_global_load_lds((const __attribute__((address_space(1))) void*)g,
                                   (__attribute__((address_space(3))) void*)l, 16, 0, 0);
}

// ---------------------------------------------------------------------------
// Kernel 1 (FUSED): per-block window = rows [16*bx,16*bx+16) x cols
// [1024*by, 1024*by+1024).  Part A: SmoothQuant + NVFP4 fake-quant -> bf16
// into A_big (exact reference fp32 math, unchanged from verified rounds).
// Part B: LoRA partial T for the same window via MFMA 16x16x32 (fragment
// math byte-identical to the verified lora_part of rounds 1-4) -> fp32
// partial Tp[by][4096][32].  x is read from HBM ONCE (quant first; the MFMA
// row-gathers then hit L1/L2, since its k-windows are subsets of the block
// window).
// ---------------------------------------------------------------------------
__global__ __launch_bounds__(256) void fused_quant_lora_kernel(
    const float* __restrict__ x, const float* __restrict__ ss,
    const float* __restrict__ la, __bf16* __restrict__ Ab,
    float* __restrict__ Tp) {
  __shared__ float red[4][16][32];
  int tid  = threadIdx.x;
  int m0   = blockIdx.x << 4;                 // 16-row strip
  int by   = blockIdx.y;                      // 1024-col k-chunk

  // ---- Part A: quant.  thread t -> row m0+(t>>4), col-blocks (t&15)+16i ----
  {
    int row = m0 + (tid >> 4);
    int cb0 = tid & 15;
#pragma unroll
    for (int i = 0; i < 4; i++) {
      int col = (by << 10) + ((cb0 + (i << 4)) << 4);
      const float4* xp = (const float4*)(x + ((size_t)row << 12) + col);
      const float4* sp = (const float4*)(ss + col);
      float xs[16];
#pragma unroll
      for (int j = 0; j < 4; j++) {
        float4 xv = xp[j]; float4 sv = sp[j];
        xs[4*j+0] = xv.x * sv.x; xs[4*j+1] = xv.y * sv.y;
        xs[4*j+2] = xv.z * sv.z; xs[4*j+3] = xv.w * sv.w;
      }
      float amax = 0.f;
#pragma unroll
      for (int j = 0; j < 16; j++) amax = fmaxf(amax, fabsf(xs[j]));
      amax = fmaxf(amax, 1e-12f);
      float scale = amax / 6.0f;              // IEEE fp32 divide, same as np
      bf16x8 o0, o1;
#pragma unroll
      for (int j = 0; j < 16; j++) {
        float a  = fabsf(xs[j]);
        float xn = a / scale;                 // IEEE fp32 divide, same as np
        float bestd = xn;                     // |xn - 0.0|
        float lvl   = 0.f;
        const float L[7] = {0.5f, 1.f, 1.5f, 2.f, 3.f, 4.f, 6.f};
#pragma unroll
        for (int l = 0; l < 7; l++) {         // strict < = first-on-tie (np)
          float d = fabsf(xn - L[l]);
          if (d < bestd) { bestd = d; lvl = L[l]; }
        }
        float mag = lvl * scale;
        float q = (xs[j] > 0.f) ? mag : ((xs[j] < 0.f) ? -mag : 0.f);
        if (j < 8) o0[j] = (__bf16)q; else o1[j-8] = (__bf16)q;
      }
      __bf16* dst = Ab + (size_t)row * KP + col;
      *(bf16x8*)dst = o0;
      *(bf16x8*)(dst + 8) = o1;
    }
  }

  // ---- Part B: LoRA partial via MFMA (verified fragment layout) ----
  {
    int wave = tid >> 6, lane = tid & 63;
    int lrow = lane & 15, kg = lane >> 4;
    int kbase = (by << 10) + (wave << 8);     // 256-wide window per wave
    f32x4 acc0 = {0.f,0.f,0.f,0.f}, acc1 = {0.f,0.f,0.f,0.f};
    const float* xrow = x + ((size_t)(m0 + lrow) << 12);
    const float* a0   = la + ((size_t)lrow << 12);
    const float* a1   = a0 + (16 << 12);
#pragma unroll
    for (int k0 = 0; k0 < 256; k0 += 32) {
      int kk = kbase + k0 + (kg << 3);
      float xv[8], sv[8], v0[8], v1[8];
      *(float4*)&xv[0] = *(const float4*)(xrow + kk);
      *(float4*)&xv[4] = *(const float4*)(xrow + kk + 4);
      *(float4*)&sv[0] = *(const float4*)(ss + kk);
      *(float4*)&sv[4] = *(const float4*)(ss + kk + 4);
      *(float4*)&v0[0] = *(const float4*)(a0 + kk);
      *(float4*)&v0[4] = *(const float4*)(a0 + kk + 4);
      *(float4*)&v1[0] = *(const float4*)(a1 + kk);
      *(float4*)&v1[4] = *(const float4*)(a1 + kk + 4);
      bf16x8 af, b0, b1;
#pragma unroll
      for (int j = 0; j < 8; j++) {
        af[j] = (__bf16)(xv[j] * sv[j]);
        b0[j] = (__bf16)v0[j];
        b1[j] = (__bf16)v1[j];
      }
      acc0 = __builtin_amdgcn_mfma_f32_16x16x32_bf16(af, b0, acc0, 0, 0, 0);
      acc1 = __builtin_amdgcn_mfma_f32_16x16x32_bf16(af, b1, acc1, 0, 0, 0);
    }
#pragma unroll
    for (int r = 0; r < 4; r++) {
      red[wave][kg*4 + r][lrow]      = acc0[r];   // verified layout (r1-r4)
      red[wave][kg*4 + r][16 + lrow] = acc1[r];
    }
    __syncthreads();
    for (int o = tid; o < 512; o += 256) {
      int rr = o >> 5, cc = o & 31;
      float s = red[0][rr][cc] + red[1][rr][cc] + red[2][rr][cc] + red[3][rr][cc];
      Tp[((size_t)by * 4096 + m0 + rr) * 32 + cc] = s;
    }
  }
}

// ---------------------------------------------------------------------------
// Kernel 2: sum the 4 K-partials, write bf16 T into A_big[:,4096:4128],
// zero the pad cols 4128:4160.
// ---------------------------------------------------------------------------
__global__ __launch_bounds__(256) void lora_fix_kernel(const float* __restrict__ Tp,
                                                       __bf16* __restrict__ Ab) {
  int id  = blockIdx.x * 256 + threadIdx.x;   // < 4096*32
  int row = id >> 5, cc = id & 31;
  float s = 0.f;
#pragma unroll
  for (int kc = 0; kc < 4; kc++)
    s += Tp[((size_t)kc * 4096 + row) * 32 + cc];
  __bf16* dst = Ab + (size_t)row * KP + 4096;
  dst[cc]      = (__bf16)s;
  dst[32 + cc] = (__bf16)0.f;
}

// ---------------------------------------------------------------------------
// Kernel 3: w fp32 -> bf16 into B_big[:, 0:4096]; lora_b -> cols 4096:4128;
// zeros -> cols 4128:4160.  Runs AFTER lora_fix (overwrites the aliased Tp).
// ---------------------------------------------------------------------------
__global__ __launch_bounds__(256) void wconv_kernel(const float* __restrict__ w,
                                                    const float* __restrict__ lb,
                                                    __bf16* __restrict__ Bb) {
  int id  = blockIdx.x * 256 + threadIdx.x;   // < 4096*520
  int row = id / 520;
  int g   = id - row * 520;
  bf16x8 v;
  if (g < 512) {
    const float4* wp = (const float4*)(w + ((size_t)row << 12) + (g << 3));
    float4 a = wp[0], b = wp[1];
    v[0]=(__bf16)a.x; v[1]=(__bf16)a.y; v[2]=(__bf16)a.z; v[3]=(__bf16)a.w;
    v[4]=(__bf16)b.x; v[5]=(__bf16)b.y; v[6]=(__bf16)b.z; v[7]=(__bf16)b.w;
  } else if (g < 516) {
    const float* p = lb + (size_t)row * 32 + ((g - 512) << 3);
#pragma unroll
    for (int j = 0; j < 8; j++) v[j] = (__bf16)p[j];
  } else {
#pragma unroll
    for (int j = 0; j < 8; j++) v[j] = (__bf16)0.f;
  }
  *(bf16x8*)(Bb + (size_t)row * KP + ((size_t)g << 3)) = v;
}

// ---------------------------------------------------------------------------
// Kernel 4: C[4096,4096] = A_big @ B_big^T + bias.  m97 structure, r3 block
// mapping RESTORED (r4's grouped swizzle raised FETCH 166->283 MB and cost
// ~5 us; gemm is not BW-bound so locality games don't pay).  Verified:
// 0 LDS bank conflicts, ~173 us, MfmaUtil 35%.
// ---------------------------------------------------------------------------
__global__ __launch_bounds__(256) void gemm_kernel(const __bf16* __restrict__ A,
                                                   const __bf16* __restrict__ B,
                                                   const float* __restrict__ bias,
                                                   float* __restrict__ C) {
  __shared__ __bf16 As[128 * 64];
  __shared__ __bf16 Bs[128 * 64];
  int tid  = threadIdx.x;
  int wave = tid >> 6, lane = tid & 63;
  int bm = blockIdx.x >> 5, bn = blockIdx.x & 31;
  size_t m0 = (size_t)bm << 7, n0 = (size_t)bn << 7;
  int wm = wave >> 1, wn = wave & 1;
  int lrow = lane & 15, kg = lane >> 4;
  int srow = lane >> 3;                       // row within 8-row staging chunk
  int sk   = ((lane & 7) ^ srow) << 3;        // swizzled k element offset
  f32x4 acc[4][4];
#pragma unroll
  for (int r = 0; r < 4; r++)
#pragma unroll
    for (int c = 0; c < 4; c++) acc[r][c] = (f32x4){0.f,0.f,0.f,0.f};

  for (int k = 0; k < KP; k += 64) {
#pragma unroll
    for (int i = 0; i < 4; i++) {
      int chunk = (wave << 2) + i;            // 16 chunks of 8 rows x 64 k
      int row   = (chunk << 3) + srow;
      async_copy16(A + (m0 + row) * (size_t)KP + k + sk, (void*)(As + chunk * 512));
      async_copy16(B + (n0 + row) * (size_t)KP + k + sk, (void*)(Bs + chunk * 512));
    }
    __syncthreads();
#pragma unroll
    for (int ks = 0; ks < 2; ks++) {
      bf16x8 af[4], bfr[4];
      int kx = ((ks << 6) + (kg << 4)) ^ ((lrow & 7) << 4);
#pragma unroll
      for (int r = 0; r < 4; r++) {
        int ml = (wm << 6) + (r << 4) + lrow;
        af[r]  = *(const bf16x8*)((const char*)As + ml * 128 + kx);
        int nl = (wn << 6) + (r << 4) + lrow;
        bfr[r] = *(const bf16x8*)((const char*)Bs + nl * 128 + kx);
      }
#pragma unroll
      for (int r = 0; r < 4; r++)
#pragma unroll
        for (int c = 0; c < 4; c++)
          acc[r][c] = __builtin_amdgcn_mfma_f32_16x16x32_bf16(af[r], bfr[c], acc[r][c], 0, 0, 0);
    }
    __syncthreads();
  }
  // epilogue: + bias, fp32 store. C frag layout: col=lane&15, row=kg*4+reg.
#pragma unroll
  for (int c = 0; c < 4; c++) {
    int col = (int)n0 + (wn << 6) + (c << 4) + lrow;
    float bv = bias[col];
#pragma unroll
    for (int r = 0; r < 4; r++) {
      size_t rowb = m0 + (wm << 6) + (r << 4) + (kg << 2);
#pragma unroll
      for (int q = 0; q < 4; q++)
        C[(rowb + q) * 4096 + col] = acc[r][c][q] + bv;
    }
  }
}

extern "C" void kernel_launch(void* const* d_in, const int* in_sizes, int n_in,
                              void* d_out, int out_size, void* d_ws, size_t ws_size,
                              hipStream_t stream) {
  const float* x    = (const float*)d_in[0];   // [2,2048,4096]
  const float* ss   = (const float*)d_in[1];   // [4096]
  const float* w    = (const float*)d_in[2];   // [4096,4096]
  const float* la   = (const float*)d_in[3];   // [32,4096]
  const float* lb   = (const float*)d_in[4];   // [4096,32]
  const float* bias = (const float*)d_in[5];   // [4096]
  float* out = (float*)d_out;                  // [2,2048,4096] fp32

  __bf16* Ab = (__bf16*)d_ws;                  // [4096, 4160] bf16  (34.1 MB)
  __bf16* Bb = Ab + (size_t)4096 * KP;         // [4096, 4160] bf16  (34.1 MB)
  // Tp ALIASES the first 2 MB of Bb — dead until wconv runs (after lora_fix).
  // Total ws usage = 136,314,880 B (proven to fit since round 1).
  float* Tp = (float*)Bb;                      // [4][4096][32] fp32 (2 MB)

  fused_quant_lora_kernel<<<dim3(256, 4), 256, 0, stream>>>(x, ss, la, Ab, Tp);
  lora_fix_kernel<<<512, 256, 0, stream>>>(Tp, Ab);
  wconv_kernel<<<8320, 256, 0, stream>>>(w, lb, Bb);       // overwrites Tp
  gemm_kernel<<<1024, 256, 0, stream>>>(Ab, Bb, bias, out);
}

// Round 6
// 349.423 us; speedup vs baseline: 1.0363x; 1.0136x over previous
//
#include <hip/hip_runtime.h>
#include <hip/hip_bf16.h>
#include <stdint.h>

typedef __attribute__((ext_vector_type(8)))  __bf16 bf16x8;
typedef __attribute__((ext_vector_type(4)))  float  f32x4;
typedef __attribute__((ext_vector_type(16))) float  f32x16;

#define KP 4160   // padded K: 4096 (quantized x) + 32 (lora T) + 32 (zero pad)

__device__ inline void async_copy16(const void* g, void* l) {
  __builtin_amdgcn_global_load_lds((const __attribute__((address_space(1))) void*)g,
                                   (__attribute__((address_space(3))) void*)l, 16, 0, 0);
}

// ---------------------------------------------------------------------------
// Kernel 1 (FUSED, verified r5): per-block window = rows [16*bx,16*bx+16) x
// cols [1024*by,1024*by+1024).  Part A: SmoothQuant + NVFP4 fake-quant ->
// bf16 into A_big (exact reference fp32 math).  Part B: LoRA partial T via
// MFMA 16x16x32 -> fp32 partial Tp[by][4096][32].  Tp now lives in d_out
// (dead until gemm overwrites it).
// ---------------------------------------------------------------------------
__global__ __launch_bounds__(256) void fused_quant_lora_kernel(
    const float* __restrict__ x, const float* __restrict__ ss,
    const float* __restrict__ la, __bf16* __restrict__ Ab,
    float* __restrict__ Tp) {
  __shared__ float red[4][16][32];
  int tid  = threadIdx.x;
  int m0   = blockIdx.x << 4;                 // 16-row strip
  int by   = blockIdx.y;                      // 1024-col k-chunk

  // ---- Part A: quant.  thread t -> row m0+(t>>4), col-blocks (t&15)+16i ----
  {
    int row = m0 + (tid >> 4);
    int cb0 = tid & 15;
#pragma unroll
    for (int i = 0; i < 4; i++) {
      int col = (by << 10) + ((cb0 + (i << 4)) << 4);
      const float4* xp = (const float4*)(x + ((size_t)row << 12) + col);
      const float4* sp = (const float4*)(ss + col);
      float xs[16];
#pragma unroll
      for (int j = 0; j < 4; j++) {
        float4 xv = xp[j]; float4 sv = sp[j];
        xs[4*j+0] = xv.x * sv.x; xs[4*j+1] = xv.y * sv.y;
        xs[4*j+2] = xv.z * sv.z; xs[4*j+3] = xv.w * sv.w;
      }
      float amax = 0.f;
#pragma unroll
      for (int j = 0; j < 16; j++) amax = fmaxf(amax, fabsf(xs[j]));
      amax = fmaxf(amax, 1e-12f);
      float scale = amax / 6.0f;              // IEEE fp32 divide, same as np
      bf16x8 o0, o1;
#pragma unroll
      for (int j = 0; j < 16; j++) {
        float a  = fabsf(xs[j]);
        float xn = a / scale;                 // IEEE fp32 divide, same as np
        float bestd = xn;                     // |xn - 0.0|
        float lvl   = 0.f;
        const float L[7] = {0.5f, 1.f, 1.5f, 2.f, 3.f, 4.f, 6.f};
#pragma unroll
        for (int l = 0; l < 7; l++) {         // strict < = first-on-tie (np)
          float d = fabsf(xn - L[l]);
          if (d < bestd) { bestd = d; lvl = L[l]; }
        }
        float mag = lvl * scale;
        float q = (xs[j] > 0.f) ? mag : ((xs[j] < 0.f) ? -mag : 0.f);
        if (j < 8) o0[j] = (__bf16)q; else o1[j-8] = (__bf16)q;
      }
      __bf16* dst = Ab + (size_t)row * KP + col;
      *(bf16x8*)dst = o0;
      *(bf16x8*)(dst + 8) = o1;
    }
  }

  // ---- Part B: LoRA partial via MFMA (verified fragment layout) ----
  {
    int wave = tid >> 6, lane = tid & 63;
    int lrow = lane & 15, kg = lane >> 4;
    int kbase = (by << 10) + (wave << 8);     // 256-wide window per wave
    f32x4 acc0 = {0.f,0.f,0.f,0.f}, acc1 = {0.f,0.f,0.f,0.f};
    const float* xrow = x + ((size_t)(m0 + lrow) << 12);
    const float* a0   = la + ((size_t)lrow << 12);
    const float* a1   = a0 + (16 << 12);
#pragma unroll
    for (int k0 = 0; k0 < 256; k0 += 32) {
      int kk = kbase + k0 + (kg << 3);
      float xv[8], sv[8], v0[8], v1[8];
      *(float4*)&xv[0] = *(const float4*)(xrow + kk);
      *(float4*)&xv[4] = *(const float4*)(xrow + kk + 4);
      *(float4*)&sv[0] = *(const float4*)(ss + kk);
      *(float4*)&sv[4] = *(const float4*)(ss + kk + 4);
      *(float4*)&v0[0] = *(const float4*)(a0 + kk);
      *(float4*)&v0[4] = *(const float4*)(a0 + kk + 4);
      *(float4*)&v1[0] = *(const float4*)(a1 + kk);
      *(float4*)&v1[4] = *(const float4*)(a1 + kk + 4);
      bf16x8 af, b0, b1;
#pragma unroll
      for (int j = 0; j < 8; j++) {
        af[j] = (__bf16)(xv[j] * sv[j]);
        b0[j] = (__bf16)v0[j];
        b1[j] = (__bf16)v1[j];
      }
      acc0 = __builtin_amdgcn_mfma_f32_16x16x32_bf16(af, b0, acc0, 0, 0, 0);
      acc1 = __builtin_amdgcn_mfma_f32_16x16x32_bf16(af, b1, acc1, 0, 0, 0);
    }
#pragma unroll
    for (int r = 0; r < 4; r++) {
      red[wave][kg*4 + r][lrow]      = acc0[r];   // verified layout (r1-r5)
      red[wave][kg*4 + r][16 + lrow] = acc1[r];
    }
    __syncthreads();
    for (int o = tid; o < 512; o += 256) {
      int rr = o >> 5, cc = o & 31;
      float s = red[0][rr][cc] + red[1][rr][cc] + red[2][rr][cc] + red[3][rr][cc];
      Tp[((size_t)by * 4096 + m0 + rr) * 32 + cc] = s;
    }
  }
}

// ---------------------------------------------------------------------------
// Kernel 2 (MERGED wconv + lora_fix): blocks [0,8320) convert w -> bf16 into
// B_big cols 0:4096, lora_b -> 4096:4128, zeros -> 4128:4160.  Blocks
// [8320,8832) sum the 4 Tp partials -> bf16 T into A_big[:,4096:4128] + zero
// pad.  Tp lives in d_out, so no aliasing hazard with Bb writes.
// ---------------------------------------------------------------------------
__global__ __launch_bounds__(256) void wconv_fix_kernel(const float* __restrict__ w,
                                                        const float* __restrict__ lb,
                                                        const float* __restrict__ Tp,
                                                        __bf16* __restrict__ Bb,
                                                        __bf16* __restrict__ Ab) {
  int b = blockIdx.x;
  if (b < 8320) {
    int id  = b * 256 + threadIdx.x;          // < 4096*520
    int row = id / 520;
    int g   = id - row * 520;
    bf16x8 v;
    if (g < 512) {
      const float4* wp = (const float4*)(w + ((size_t)row << 12) + (g << 3));
      float4 a = wp[0], bb = wp[1];
      v[0]=(__bf16)a.x;  v[1]=(__bf16)a.y;  v[2]=(__bf16)a.z;  v[3]=(__bf16)a.w;
      v[4]=(__bf16)bb.x; v[5]=(__bf16)bb.y; v[6]=(__bf16)bb.z; v[7]=(__bf16)bb.w;
    } else if (g < 516) {
      const float* p = lb + (size_t)row * 32 + ((g - 512) << 3);
#pragma unroll
      for (int j = 0; j < 8; j++) v[j] = (__bf16)p[j];
    } else {
#pragma unroll
      for (int j = 0; j < 8; j++) v[j] = (__bf16)0.f;
    }
    *(bf16x8*)(Bb + (size_t)row * KP + ((size_t)g << 3)) = v;
  } else {
    int id  = (b - 8320) * 256 + threadIdx.x; // < 4096*32
    int row = id >> 5, cc = id & 31;
    float s = 0.f;
#pragma unroll
    for (int kc = 0; kc < 4; kc++)
      s += Tp[((size_t)kc * 4096 + row) * 32 + cc];
    __bf16* dst = Ab + (size_t)row * KP + 4096;
    dst[cc]      = (__bf16)s;
    dst[32 + cc] = (__bf16)0.f;
  }
}

// ---------------------------------------------------------------------------
// Kernel 3: C[4096,4096] = A_big @ B_big^T + bias.  m97 staging structure
// (verified r1-r5: 0 LDS bank conflicts), NEW: 32x32x16 bf16 MFMA (2382 TF
// ubench vs 2075 for 16x16x32; half the MFMA issue slots).  Per wave: 64x64
// output = 2x2 frags of 32x32, f32x16 acc each.  A/B frag: m(or n)=lane&31,
// k=(lane>>5)*8+j.  C/D (HW-verified m74/m101): col=lane&31,
// row=(reg&3)+8*(reg>>2)+4*(lane>>5).
// ---------------------------------------------------------------------------
__global__ __launch_bounds__(256) void gemm_kernel(const __bf16* __restrict__ A,
                                                   const __bf16* __restrict__ B,
                                                   const float* __restrict__ bias,
                                                   float* __restrict__ C) {
  __shared__ __bf16 As[128 * 64];
  __shared__ __bf16 Bs[128 * 64];
  int tid  = threadIdx.x;
  int wave = tid >> 6, lane = tid & 63;
  int bm = blockIdx.x >> 5, bn = blockIdx.x & 31;
  size_t m0 = (size_t)bm << 7, n0 = (size_t)bn << 7;
  int wm = wave >> 1, wn = wave & 1;
  int ln31 = lane & 31, kgrp = lane >> 5;
  int srow = lane >> 3;                       // row within 8-row staging chunk
  int sk   = ((lane & 7) ^ srow) << 3;        // swizzled k element offset
  int swz  = (ln31 & 7) << 4;                 // per-row XOR for frag reads
  f32x16 acc[2][2];
#pragma unroll
  for (int r = 0; r < 2; r++)
#pragma unroll
    for (int c = 0; c < 2; c++)
#pragma unroll
      for (int q = 0; q < 16; q++) acc[r][c][q] = 0.f;

  for (int k = 0; k < KP; k += 64) {
#pragma unroll
    for (int i = 0; i < 4; i++) {
      int chunk = (wave << 2) + i;            // 16 chunks of 8 rows x 64 k
      int row   = (chunk << 3) + srow;
      async_copy16(A + (m0 + row) * (size_t)KP + k + sk, (void*)(As + chunk * 512));
      async_copy16(B + (n0 + row) * (size_t)KP + k + sk, (void*)(Bs + chunk * 512));
    }
    __syncthreads();
#pragma unroll
    for (int t = 0; t < 4; t++) {             // 4 k-steps of 16
      int kx = ((t << 5) + (kgrp << 4)) ^ swz;  // (row&7) == (ln31&7) for all frag rows
      bf16x8 af[2], bfr[2];
#pragma unroll
      for (int h = 0; h < 2; h++) {
        int arow = (wm << 6) + (h << 5) + ln31;
        af[h]  = *(const bf16x8*)((const char*)As + arow * 128 + kx);
        int brow = (wn << 6) + (h << 5) + ln31;
        bfr[h] = *(const bf16x8*)((const char*)Bs + brow * 128 + kx);
      }
#pragma unroll
      for (int r = 0; r < 2; r++)
#pragma unroll
        for (int c = 0; c < 2; c++)
          acc[r][c] = __builtin_amdgcn_mfma_f32_32x32x16_bf16(af[r], bfr[c], acc[r][c], 0, 0, 0);
    }
    __syncthreads();
  }
  // epilogue: + bias, fp32 store.
#pragma unroll
  for (int c = 0; c < 2; c++) {
    int col = (int)n0 + (wn << 6) + (c << 5) + ln31;
    float bv = bias[col];
#pragma unroll
    for (int r = 0; r < 2; r++) {
      size_t rowb = m0 + (wm << 6) + (r << 5) + (kgrp << 2);
#pragma unroll
      for (int q = 0; q < 16; q++) {
        size_t row = rowb + (q & 3) + ((q >> 2) << 3);
        C[row * 4096 + col] = acc[r][c][q] + bv;
      }
    }
  }
}

extern "C" void kernel_launch(void* const* d_in, const int* in_sizes, int n_in,
                              void* d_out, int out_size, void* d_ws, size_t ws_size,
                              hipStream_t stream) {
  const float* x    = (const float*)d_in[0];   // [2,2048,4096]
  const float* ss   = (const float*)d_in[1];   // [4096]
  const float* w    = (const float*)d_in[2];   // [4096,4096]
  const float* la   = (const float*)d_in[3];   // [32,4096]
  const float* lb   = (const float*)d_in[4];   // [4096,32]
  const float* bias = (const float*)d_in[5];   // [4096]
  float* out = (float*)d_out;                  // [2,2048,4096] fp32

  __bf16* Ab = (__bf16*)d_ws;                  // [4096, 4160] bf16  (34.1 MB)
  __bf16* Bb = Ab + (size_t)4096 * KP;         // [4096, 4160] bf16  (34.1 MB)
  // Tp lives in d_out scratch space: 4*4096*32*4 = 2 MB << 67 MB.  It is
  // consumed by wconv_fix and then d_out is fully overwritten by gemm.
  float* Tp = out;                             // [4][4096][32] fp32 (2 MB)

  fused_quant_lora_kernel<<<dim3(256, 4), 256, 0, stream>>>(x, ss, la, Ab, Tp);
  wconv_fix_kernel<<<8832, 256, 0, stream>>>(w, lb, Tp, Bb, Ab);
  gemm_kernel<<<1024, 256, 0, stream>>>(Ab, Bb, bias, out);
}